// Round 5
// baseline (153.496 us; speedup 1.0000x reference)
//
#include <hip/hip_runtime.h>

#define NF 13          // y = [1, x1..x12]
#define NEXP 454       // unique monomials
#define NROWS 65536
#define BN_EPS 1e-5f
#define NBLK 512               // fused-kernel blocks (2/CU on 256 CUs -> co-resident)
#define BROWS (NROWS / NBLK)   // 128 rows per block
#define PARTW 908              // per-block partial row: [454 sums | 454 sumsqs]
#define SPAD (BROWS + 4)       // padded column stride: 132 words, 16B-aligned
#define FIN_FPB 32             // features per finalize block

// Decode feature index j (0..453) -> nondecreasing triple (i0<=i1<=i2),
// lexicographic order over (i0,i1,i2), skipping (0,0,0).
__device__ __forceinline__ void decode_triple(int j, int& i0, int& i1, int& i2) {
    int g = j + 1;
    i0 = 0;
    for (;;) {
        int m = NF - i0;
        int c = m * (m + 1) / 2;
        if (g < c) break;
        g -= c; ++i0;
    }
    i1 = i0;
    for (;;) {
        int m = NF - i1;
        if (g < m) break;
        g -= m; ++i1;
    }
    i2 = i1 + g;
}

// Software grid barrier: device-scope arrive, agent-scope acquire spin.
// Safe iff all NBLK blocks are co-resident (guaranteed: 2 blocks/CU needed,
// launch_bounds caps VGPR so occupancy >= 2/CU).
__device__ __forceinline__ void grid_bar(int* ctr, int n) {
    __syncthreads();
    if (threadIdx.x == 0) {
        __threadfence();   // make this block's global writes visible
        __hip_atomic_fetch_add(ctr, 1, __ATOMIC_ACQ_REL, __HIP_MEMORY_SCOPE_AGENT);
        while (__hip_atomic_load(ctr, __ATOMIC_ACQUIRE, __HIP_MEMORY_SCOPE_AGENT) < n) {
            __builtin_amdgcn_s_sleep(2);
        }
        __threadfence();   // acquire all blocks' writes
    }
    __syncthreads();
}

// Node 1: zero the two barrier counters (ws is poisoned 0xAA before timing).
__global__ void zero_ctr_kernel(int* __restrict__ ctr) {
    if (threadIdx.x < 2) ctr[threadIdx.x] = 0;
}

// Node 2: stats -> barrier -> finalize -> barrier -> write, LDS staged ONCE.
__global__ __launch_bounds__(256, 2) void fused_kernel(
        const float* __restrict__ x,
        const float* __restrict__ w,
        const float* __restrict__ b,
        float* __restrict__ part,    // NBLK * PARTW floats
        float* __restrict__ ss,      // 2*NEXP floats: scale | shift
        int* __restrict__ ctr,       // 2 ints: barrier counters
        float* __restrict__ out) {
    __shared__ float yc[NF][SPAD];
    __shared__ float reds[8][FIN_FPB];
    __shared__ float redq[8][FIN_FPB];
    const int tid = threadIdx.x;
    const int blk = blockIdx.x;
    const int row0 = blk * BROWS;

    // ---- Stage 128 rows column-major (coalesced read of 12*BROWS floats) ----
    for (int idx = tid; idx < BROWS * 12; idx += 256) {
        int r = idx / 12, c = idx - r * 12;
        yc[c + 1][r] = x[(size_t)row0 * 12 + idx];
    }
    for (int r = tid; r < BROWS; r += 256) yc[0][r] = 1.0f;
    __syncthreads();

    const int j0 = tid;
    const int j1 = tid + 256;
    const bool has1 = (j1 < NEXP);
    int a0, a1, a2, b0 = 0, b1 = 0, b2 = 0;
    decode_triple(j0, a0, a1, a2);
    if (has1) decode_triple(j1, b0, b1, b2);

    // ---- Phase A: per-block partial sum / sumsq ----
    float s0 = 0.f, q0 = 0.f, s1 = 0.f, q1 = 0.f;
    for (int r = 0; r < BROWS; r += 4) {
        float4 va = *reinterpret_cast<const float4*>(&yc[a0][r]);
        float4 vb = *reinterpret_cast<const float4*>(&yc[a1][r]);
        float4 vc = *reinterpret_cast<const float4*>(&yc[a2][r]);
        float f;
        f = va.x * vb.x * vc.x; s0 += f; q0 += f * f;
        f = va.y * vb.y * vc.y; s0 += f; q0 += f * f;
        f = va.z * vb.z * vc.z; s0 += f; q0 += f * f;
        f = va.w * vb.w * vc.w; s0 += f; q0 += f * f;
        if (has1) {
            float4 wa = *reinterpret_cast<const float4*>(&yc[b0][r]);
            float4 wb = *reinterpret_cast<const float4*>(&yc[b1][r]);
            float4 wc = *reinterpret_cast<const float4*>(&yc[b2][r]);
            f = wa.x * wb.x * wc.x; s1 += f; q1 += f * f;
            f = wa.y * wb.y * wc.y; s1 += f; q1 += f * f;
            f = wa.z * wb.z * wc.z; s1 += f; q1 += f * f;
            f = wa.w * wb.w * wc.w; s1 += f; q1 += f * f;
        }
    }
    {
        float* p = part + (size_t)blk * PARTW;
        p[j0] = s0;
        p[NEXP + j0] = q0;
        if (has1) {
            p[j1] = s1;
            p[NEXP + j1] = q1;
        }
    }

    grid_bar(&ctr[0], NBLK);

    // ---- Phase B: blocks 0..14 reduce partials, fold BN into scale/shift ----
    if (blk < (NEXP + FIN_FPB - 1) / FIN_FPB) {
        const int fl = tid & 31;
        const int k  = tid >> 5;               // slice 0..7
        const int f  = blk * FIN_FPB + fl;
        float s = 0.f, q = 0.f;
        if (f < NEXP) {
            #pragma unroll 4
            for (int i = 0; i < NBLK / 8; ++i) {
                const float* p = part + (size_t)(k * (NBLK / 8) + i) * PARTW;
                s += p[f];
                q += p[NEXP + f];
            }
        }
        reds[k][fl] = s;
        redq[k][fl] = q;
        __syncthreads();
        if (tid < FIN_FPB && f < NEXP) {
            float ts = 0.f, tq = 0.f;
            #pragma unroll
            for (int kk = 0; kk < 8; ++kk) { ts += reds[kk][fl]; tq += redq[kk][fl]; }
            const float inv_n = 1.0f / (float)NROWS;
            float mean = ts * inv_n;
            float var  = tq * inv_n - mean * mean;
            float scale = rsqrtf(var + BN_EPS) * w[f];
            ss[f] = scale;
            ss[NEXP + f] = b[f] - mean * scale;
        }
    }

    grid_bar(&ctr[1], NBLK);

    // ---- Phase C: write from the still-resident LDS tile ----
    const float sc0 = ss[j0], sh0 = ss[NEXP + j0];
    const float sc1 = has1 ? ss[j1] : 0.f, sh1 = has1 ? ss[NEXP + j1] : 0.f;

    for (int r = 0; r < BROWS; r += 4) {
        float4 va = *reinterpret_cast<const float4*>(&yc[a0][r]);
        float4 vb = *reinterpret_cast<const float4*>(&yc[a1][r]);
        float4 vc = *reinterpret_cast<const float4*>(&yc[a2][r]);
        float* o = out + (size_t)(row0 + r) * NEXP + j0;
        o[0 * NEXP] = va.x * vb.x * vc.x * sc0 + sh0;
        o[1 * NEXP] = va.y * vb.y * vc.y * sc0 + sh0;
        o[2 * NEXP] = va.z * vb.z * vc.z * sc0 + sh0;
        o[3 * NEXP] = va.w * vb.w * vc.w * sc0 + sh0;
        if (has1) {
            float4 wa = *reinterpret_cast<const float4*>(&yc[b0][r]);
            float4 wb = *reinterpret_cast<const float4*>(&yc[b1][r]);
            float4 wc = *reinterpret_cast<const float4*>(&yc[b2][r]);
            float* o1 = out + (size_t)(row0 + r) * NEXP + j1;
            o1[0 * NEXP] = wa.x * wb.x * wc.x * sc1 + sh1;
            o1[1 * NEXP] = wa.y * wb.y * wc.y * sc1 + sh1;
            o1[2 * NEXP] = wa.z * wb.z * wc.z * sc1 + sh1;
            o1[3 * NEXP] = wa.w * wb.w * wc.w * sc1 + sh1;
        }
    }
}

extern "C" void kernel_launch(void* const* d_in, const int* in_sizes, int n_in,
                              void* d_out, int out_size, void* d_ws, size_t ws_size,
                              hipStream_t stream) {
    const float* x  = (const float*)d_in[0];
    const float* bw = (const float*)d_in[1];
    const float* bb = (const float*)d_in[2];
    float* out  = (float*)d_out;
    float* part = (float*)d_ws;                    // NBLK*908 floats = 1.86 MB
    float* ss   = part + (size_t)NBLK * PARTW;     // 908 floats scale/shift
    int*   ctr  = (int*)(ss + 2 * NEXP);           // 2 barrier counters

    zero_ctr_kernel<<<1, 64, 0, stream>>>(ctr);
    fused_kernel<<<NBLK, 256, 0, stream>>>(x, bw, bb, part, ss, ctr, out);
}

// Round 6
// 62.909 us; speedup vs baseline: 2.4400x; 2.4400x over previous
//
#include <hip/hip_runtime.h>

#define NF 13          // y = [1, x1..x12]
#define NEXP 454       // unique monomials
#define NROWS 65536
#define BN_EPS 1e-5f
#define SBLK 512               // stats blocks
#define SROWS (NROWS / SBLK)   // 128 rows per stats block
#define PARTW 908              // per-block partial row: [454 sums | 454 sumsqs]
#define SPAD (SROWS + 4)       // padded column stride: 132 words, 16B-aligned
#define WROWS 64               // rows per write block
#define WPAD (WROWS + 4)       // 68 words
#define FIN_FPB 32             // features per finalize block

// Map thread -> (A0, A1, I2, CNT, JF): this thread owns features
// JF (= monomial (A0,A1,I2)) and JF+1 (= (A0,A1,I2+1)) when CNT==2.
// Pairs share the prefix y[A0]*y[A1], and their output indices are adjacent.
// Exactly 251 threads get CNT>0 (sum over 91 (i0,i1)-groups of ceil(L/2)).
__device__ __forceinline__ void thread_features(int tid, int& A0, int& A1,
                                                int& I2, int& CNT, int& JF) {
    int trem = tid, j = 0;
    A0 = A1 = I2 = JF = 0; CNT = 0;
    for (int i0v = 0; i0v < NF && CNT == 0; ++i0v) {
        for (int i1v = i0v; i1v < NF; ++i1v) {
            int i2s = (i0v == 0 && i1v == 0) ? 1 : i1v;  // skip (0,0,0)
            int L = NF - i2s;             // features in this (i0,i1) group
            int nth = (L + 1) >> 1;       // thread slots for this group
            if (trem < nth) {
                A0 = i0v; A1 = i1v;
                I2 = i2s + 2 * trem;
                CNT = (I2 < NF - 1) ? 2 : 1;
                JF = j + 2 * trem;
                break;
            }
            trem -= nth; j += L;
        }
    }
}

// ---------------- Pass 1: per-block partial sum / sumsq (no atomics) --------
__global__ __launch_bounds__(256) void stats_kernel(const float* __restrict__ x,
                                                    float* __restrict__ part) {
    __shared__ float yc[NF][SPAD];
    const int tid = threadIdx.x;
    const int row0 = blockIdx.x * SROWS;

    for (int idx = tid; idx < SROWS * 12; idx += 256) {
        int r = idx / 12, c = idx - r * 12;
        yc[c + 1][r] = x[(size_t)row0 * 12 + idx];
    }
    for (int r = tid; r < SROWS; r += 256) yc[0][r] = 1.0f;
    __syncthreads();

    int A0, A1, I2, CNT, JF;
    thread_features(tid, A0, A1, I2, CNT, JF);

    float s0 = 0.f, q0 = 0.f, s1 = 0.f, q1 = 0.f;
    if (CNT > 0) {
        for (int r = 0; r < SROWS; r += 4) {
            float4 va = *reinterpret_cast<const float4*>(&yc[A0][r]);
            float4 vb = *reinterpret_cast<const float4*>(&yc[A1][r]);
            float4 vc = *reinterpret_cast<const float4*>(&yc[I2][r]);
            float px = va.x * vb.x, py = va.y * vb.y;
            float pz = va.z * vb.z, pw = va.w * vb.w;
            float f;
            f = px * vc.x; s0 += f; q0 += f * f;
            f = py * vc.y; s0 += f; q0 += f * f;
            f = pz * vc.z; s0 += f; q0 += f * f;
            f = pw * vc.w; s0 += f; q0 += f * f;
            if (CNT == 2) {
                float4 vd = *reinterpret_cast<const float4*>(&yc[I2 + 1][r]);
                f = px * vd.x; s1 += f; q1 += f * f;
                f = py * vd.y; s1 += f; q1 += f * f;
                f = pz * vd.z; s1 += f; q1 += f * f;
                f = pw * vd.w; s1 += f; q1 += f * f;
            }
        }
        float* p = part + (size_t)blockIdx.x * PARTW;
        p[JF] = s0;
        p[NEXP + JF] = q0;
        if (CNT == 2) {
            p[JF + 1] = s1;
            p[NEXP + JF + 1] = q1;
        }
    }
}

// ---------------- Pass 2: reduce partials, fold BN into scale/shift ---------
__global__ __launch_bounds__(256) void finalize_kernel(const float* __restrict__ part,
                                                       const float* __restrict__ w,
                                                       const float* __restrict__ b,
                                                       float* __restrict__ ss) {
    __shared__ float reds[8][FIN_FPB];
    __shared__ float redq[8][FIN_FPB];
    const int fl = threadIdx.x & 31;
    const int k  = threadIdx.x >> 5;              // slice 0..7
    const int f  = blockIdx.x * FIN_FPB + fl;
    float s = 0.f, q = 0.f;
    if (f < NEXP) {
        #pragma unroll 4
        for (int i = 0; i < SBLK / 8; ++i) {
            const float* p = part + (size_t)(k * (SBLK / 8) + i) * PARTW;
            s += p[f];
            q += p[NEXP + f];
        }
    }
    reds[k][fl] = s;
    redq[k][fl] = q;
    __syncthreads();
    if (threadIdx.x < FIN_FPB && f < NEXP) {
        float ts = 0.f, tq = 0.f;
        #pragma unroll
        for (int kk = 0; kk < 8; ++kk) { ts += reds[kk][fl]; tq += redq[kk][fl]; }
        const float inv_n = 1.0f / (float)NROWS;
        float mean = ts * inv_n;
        float var  = tq * inv_n - mean * mean;
        float scale = rsqrtf(var + BN_EPS) * w[f];
        ss[f] = scale;
        ss[NEXP + f] = b[f] - mean * scale;
    }
}

// ---------------- Pass 3: recompute feats, apply affine, store --------------
__global__ __launch_bounds__(256) void write_kernel(const float* __restrict__ x,
                                                    const float* __restrict__ ss,
                                                    float* __restrict__ out) {
    __shared__ float yc[NF][WPAD];
    const int tid = threadIdx.x;
    const int row0 = blockIdx.x * WROWS;

    for (int idx = tid; idx < WROWS * 12; idx += 256) {
        int r = idx / 12, c = idx - r * 12;
        yc[c + 1][r] = x[(size_t)row0 * 12 + idx];
    }
    for (int r = tid; r < WROWS; r += 256) yc[0][r] = 1.0f;

    int A0, A1, I2, CNT, JF;
    thread_features(tid, A0, A1, I2, CNT, JF);
    const float sc0 = ss[JF], sh0 = ss[NEXP + JF];
    const float sc1 = (CNT == 2) ? ss[JF + 1] : 0.f;
    const float sh1 = (CNT == 2) ? ss[NEXP + JF + 1] : 0.f;
    __syncthreads();

    if (CNT > 0) {
        for (int r = 0; r < WROWS; r += 4) {
            float4 va = *reinterpret_cast<const float4*>(&yc[A0][r]);
            float4 vb = *reinterpret_cast<const float4*>(&yc[A1][r]);
            float4 vc = *reinterpret_cast<const float4*>(&yc[I2][r]);
            float px = va.x * vb.x, py = va.y * vb.y;
            float pz = va.z * vb.z, pw = va.w * vb.w;
            float* o = out + (size_t)(row0 + r) * NEXP + JF;
            if (CNT == 2) {
                float4 vd = *reinterpret_cast<const float4*>(&yc[I2 + 1][r]);
                o[0 * NEXP]     = px * vc.x * sc0 + sh0;
                o[0 * NEXP + 1] = px * vd.x * sc1 + sh1;
                o[1 * NEXP]     = py * vc.y * sc0 + sh0;
                o[1 * NEXP + 1] = py * vd.y * sc1 + sh1;
                o[2 * NEXP]     = pz * vc.z * sc0 + sh0;
                o[2 * NEXP + 1] = pz * vd.z * sc1 + sh1;
                o[3 * NEXP]     = pw * vc.w * sc0 + sh0;
                o[3 * NEXP + 1] = pw * vd.w * sc1 + sh1;
            } else {
                o[0 * NEXP] = px * vc.x * sc0 + sh0;
                o[1 * NEXP] = py * vc.y * sc0 + sh0;
                o[2 * NEXP] = pz * vc.z * sc0 + sh0;
                o[3 * NEXP] = pw * vc.w * sc0 + sh0;
            }
        }
    }
}

extern "C" void kernel_launch(void* const* d_in, const int* in_sizes, int n_in,
                              void* d_out, int out_size, void* d_ws, size_t ws_size,
                              hipStream_t stream) {
    const float* x  = (const float*)d_in[0];
    const float* bw = (const float*)d_in[1];
    const float* bb = (const float*)d_in[2];
    float* out  = (float*)d_out;
    float* part = (float*)d_ws;                    // SBLK*908 floats = 1.86 MB
    float* ss   = part + (size_t)SBLK * PARTW;     // 908 floats scale/shift

    stats_kernel<<<SBLK, 256, 0, stream>>>(x, part);
    finalize_kernel<<<(NEXP + FIN_FPB - 1) / FIN_FPB, 256, 0, stream>>>(part, bw, bb, ss);
    write_kernel<<<NROWS / WROWS, 256, 0, stream>>>(x, ss, out);
}

// Round 7
// 56.610 us; speedup vs baseline: 2.7115x; 1.1113x over previous
//
#include <hip/hip_runtime.h>

#define NF 13          // y = [1, x1..x12]
#define NEXP 454       // unique monomials
#define NROWS 65536
#define BN_EPS 1e-5f
#define SBLK 512               // stats blocks
#define SROWS (NROWS / SBLK)   // 128 rows per stats block
#define PARTW 908              // per-block partial row: [454 sums | 454 sumsqs]
#define SPAD (SROWS + 4)       // padded column stride: 132 words, 16B-aligned
#define WROWS 64               // rows per write block
#define WPAD (WROWS + 4)       // 68 words
#define FIN_FPB 32             // features per finalize block

// Decode feature index j (0..453) -> nondecreasing triple (i0<=i1<=i2),
// lexicographic order over (i0,i1,i2), skipping (0,0,0).
__device__ __forceinline__ void decode_triple(int j, int& i0, int& i1, int& i2) {
    int g = j + 1;
    i0 = 0;
    for (;;) {
        int m = NF - i0;
        int c = m * (m + 1) / 2;
        if (g < c) break;
        g -= c; ++i0;
    }
    i1 = i0;
    for (;;) {
        int m = NF - i1;
        if (g < m) break;
        g -= m; ++i1;
    }
    i2 = i1 + g;
}

// Stats-kernel mapping: thread -> (A0,A1,I2,CNT,JF); owns features JF
// (=(A0,A1,I2)) and JF+1 (=(A0,A1,I2+1)) when CNT==2. Pairs share the
// prefix y[A0]*y[A1] -> 4 ds_read_b128 per 4 rows instead of 6.
__device__ __forceinline__ void thread_features(int tid, int& A0, int& A1,
                                                int& I2, int& CNT, int& JF) {
    int trem = tid, j = 0;
    A0 = A1 = I2 = JF = 0; CNT = 0;
    for (int i0v = 0; i0v < NF && CNT == 0; ++i0v) {
        for (int i1v = i0v; i1v < NF; ++i1v) {
            int i2s = (i0v == 0 && i1v == 0) ? 1 : i1v;  // skip (0,0,0)
            int L = NF - i2s;
            int nth = (L + 1) >> 1;
            if (trem < nth) {
                A0 = i0v; A1 = i1v;
                I2 = i2s + 2 * trem;
                CNT = (I2 < NF - 1) ? 2 : 1;
                JF = j + 2 * trem;
                break;
            }
            trem -= nth; j += L;
        }
    }
}

// ---------------- Pass 1: per-block partial sum / sumsq (no atomics) --------
__global__ __launch_bounds__(256) void stats_kernel(const float* __restrict__ x,
                                                    float* __restrict__ part) {
    __shared__ float yc[NF][SPAD];
    const int tid = threadIdx.x;
    const int row0 = blockIdx.x * SROWS;

    for (int idx = tid; idx < SROWS * 12; idx += 256) {
        int r = idx / 12, c = idx - r * 12;
        yc[c + 1][r] = x[(size_t)row0 * 12 + idx];
    }
    for (int r = tid; r < SROWS; r += 256) yc[0][r] = 1.0f;
    __syncthreads();

    int A0, A1, I2, CNT, JF;
    thread_features(tid, A0, A1, I2, CNT, JF);

    float s0 = 0.f, q0 = 0.f, s1 = 0.f, q1 = 0.f;
    if (CNT > 0) {
        for (int r = 0; r < SROWS; r += 4) {
            float4 va = *reinterpret_cast<const float4*>(&yc[A0][r]);
            float4 vb = *reinterpret_cast<const float4*>(&yc[A1][r]);
            float4 vc = *reinterpret_cast<const float4*>(&yc[I2][r]);
            float px = va.x * vb.x, py = va.y * vb.y;
            float pz = va.z * vb.z, pw = va.w * vb.w;
            float f;
            f = px * vc.x; s0 += f; q0 += f * f;
            f = py * vc.y; s0 += f; q0 += f * f;
            f = pz * vc.z; s0 += f; q0 += f * f;
            f = pw * vc.w; s0 += f; q0 += f * f;
            if (CNT == 2) {
                float4 vd = *reinterpret_cast<const float4*>(&yc[I2 + 1][r]);
                f = px * vd.x; s1 += f; q1 += f * f;
                f = py * vd.y; s1 += f; q1 += f * f;
                f = pz * vd.z; s1 += f; q1 += f * f;
                f = pw * vd.w; s1 += f; q1 += f * f;
            }
        }
        float* p = part + (size_t)blockIdx.x * PARTW;
        p[JF] = s0;
        p[NEXP + JF] = q0;
        if (CNT == 2) {
            p[JF + 1] = s1;
            p[NEXP + JF + 1] = q1;
        }
    }
}

// ---------------- Pass 2: reduce partials, fold BN into scale/shift ---------
__global__ __launch_bounds__(256) void finalize_kernel(const float* __restrict__ part,
                                                       const float* __restrict__ w,
                                                       const float* __restrict__ b,
                                                       float* __restrict__ ss) {
    __shared__ float reds[8][FIN_FPB];
    __shared__ float redq[8][FIN_FPB];
    const int fl = threadIdx.x & 31;
    const int k  = threadIdx.x >> 5;              // slice 0..7
    const int f  = blockIdx.x * FIN_FPB + fl;
    float s = 0.f, q = 0.f;
    if (f < NEXP) {
        #pragma unroll 4
        for (int i = 0; i < SBLK / 8; ++i) {
            const float* p = part + (size_t)(k * (SBLK / 8) + i) * PARTW;
            s += p[f];
            q += p[NEXP + f];
        }
    }
    reds[k][fl] = s;
    redq[k][fl] = q;
    __syncthreads();
    if (threadIdx.x < FIN_FPB && f < NEXP) {
        float ts = 0.f, tq = 0.f;
        #pragma unroll
        for (int kk = 0; kk < 8; ++kk) { ts += reds[kk][fl]; tq += redq[kk][fl]; }
        const float inv_n = 1.0f / (float)NROWS;
        float mean = ts * inv_n;
        float var  = tq * inv_n - mean * mean;
        float scale = rsqrtf(var + BN_EPS) * w[f];
        ss[f] = scale;
        ss[NEXP + f] = b[f] - mean * scale;
    }
}

// ---------------- Pass 3: recompute feats, apply affine, store --------------
// Thread t<227 owns FLAT features (2t, 2t+1): always-even index -> aligned
// float2 stores, dense 8B/lane wave pattern, half the store instructions.
__global__ __launch_bounds__(256) void write_kernel(const float* __restrict__ x,
                                                    const float* __restrict__ ss,
                                                    float* __restrict__ out) {
    __shared__ float yc[NF][WPAD];
    const int tid = threadIdx.x;
    const int row0 = blockIdx.x * WROWS;

    for (int idx = tid; idx < WROWS * 12; idx += 256) {
        int r = idx / 12, c = idx - r * 12;
        yc[c + 1][r] = x[(size_t)row0 * 12 + idx];
    }
    for (int r = tid; r < WROWS; r += 256) yc[0][r] = 1.0f;

    const bool act = tid < NEXP / 2;     // 227 active threads
    const int j0 = 2 * tid;
    int a0 = 0, a1 = 0, a2 = 0, b0 = 0, b1 = 0, b2 = 0;
    float2 sc = {0.f, 0.f}, sh = {0.f, 0.f};
    if (act) {
        decode_triple(j0, a0, a1, a2);
        decode_triple(j0 + 1, b0, b1, b2);
        sc = *reinterpret_cast<const float2*>(&ss[j0]);          // even idx
        sh = *reinterpret_cast<const float2*>(&ss[NEXP + j0]);   // even idx
    }
    __syncthreads();

    if (act) {
        for (int r = 0; r < WROWS; r += 4) {
            float4 va = *reinterpret_cast<const float4*>(&yc[a0][r]);
            float4 vb = *reinterpret_cast<const float4*>(&yc[a1][r]);
            float4 vc = *reinterpret_cast<const float4*>(&yc[a2][r]);
            float4 wa = *reinterpret_cast<const float4*>(&yc[b0][r]);
            float4 wb = *reinterpret_cast<const float4*>(&yc[b1][r]);
            float4 wc = *reinterpret_cast<const float4*>(&yc[b2][r]);
            // (row*454 + j0) is even -> float2-aligned; row stride = 227 float2
            float2* o = reinterpret_cast<float2*>(
                out + (size_t)(row0 + r) * NEXP + j0);
            o[0 * (NEXP / 2)] = {va.x * vb.x * vc.x * sc.x + sh.x,
                                 wa.x * wb.x * wc.x * sc.y + sh.y};
            o[1 * (NEXP / 2)] = {va.y * vb.y * vc.y * sc.x + sh.x,
                                 wa.y * wb.y * wc.y * sc.y + sh.y};
            o[2 * (NEXP / 2)] = {va.z * vb.z * vc.z * sc.x + sh.x,
                                 wa.z * wb.z * wc.z * sc.y + sh.y};
            o[3 * (NEXP / 2)] = {va.w * vb.w * vc.w * sc.x + sh.x,
                                 wa.w * wb.w * wc.w * sc.y + sh.y};
        }
    }
}

extern "C" void kernel_launch(void* const* d_in, const int* in_sizes, int n_in,
                              void* d_out, int out_size, void* d_ws, size_t ws_size,
                              hipStream_t stream) {
    const float* x  = (const float*)d_in[0];
    const float* bw = (const float*)d_in[1];
    const float* bb = (const float*)d_in[2];
    float* out  = (float*)d_out;
    float* part = (float*)d_ws;                    // SBLK*908 floats = 1.86 MB
    float* ss   = part + (size_t)SBLK * PARTW;     // 908 floats scale/shift

    stats_kernel<<<SBLK, 256, 0, stream>>>(x, part);
    finalize_kernel<<<(NEXP + FIN_FPB - 1) / FIN_FPB, 256, 0, stream>>>(part, bw, bb, ss);
    write_kernel<<<NROWS / WROWS, 256, 0, stream>>>(x, ss, out);
}

// Round 8
// 44.457 us; speedup vs baseline: 3.4527x; 1.2734x over previous
//
#include <hip/hip_runtime.h>

#define NF 13          // y = [1, x1..x12]
#define NEXP 454       // unique monomials
#define NROWS 65536
#define BN_EPS 1e-5f
#define SBLK 512               // stats blocks
#define SROWS (NROWS / SBLK)   // 128 rows per stats block
#define PARTW 908              // per-block partial row: [454 sums | 454 sumsqs]
#define SPAD (SROWS + 4)       // padded column stride: 132 words, 16B-aligned
#define WROWS 32               // rows per write block (R4 had 64; 2048 blocks
                               // = 8 blocks/CU = 32 waves/CU for store latency)
#define WPAD (WROWS + 4)       // 36 words
#define FIN_FPB 32             // features per finalize block

// Decode feature index j (0..453) -> nondecreasing triple (i0<=i1<=i2),
// lexicographic order over (i0,i1,i2), skipping (0,0,0).
__device__ __forceinline__ void decode_triple(int j, int& i0, int& i1, int& i2) {
    int g = j + 1;
    i0 = 0;
    for (;;) {
        int m = NF - i0;
        int c = m * (m + 1) / 2;
        if (g < c) break;
        g -= c; ++i0;
    }
    i1 = i0;
    for (;;) {
        int m = NF - i1;
        if (g < m) break;
        g -= m; ++i1;
    }
    i2 = i1 + g;
}

// ---------------- Pass 1: per-block partial sum / sumsq (no atomics) --------
__global__ __launch_bounds__(256) void stats_kernel(const float* __restrict__ x,
                                                    float* __restrict__ part) {
    __shared__ float yc[NF][SPAD];
    const int tid = threadIdx.x;
    const int row0 = blockIdx.x * SROWS;

    for (int idx = tid; idx < SROWS * 12; idx += 256) {
        int r = idx / 12, c = idx - r * 12;
        yc[c + 1][r] = x[(size_t)row0 * 12 + idx];
    }
    for (int r = tid; r < SROWS; r += 256) yc[0][r] = 1.0f;
    __syncthreads();

    const int j0 = tid;
    const int j1 = tid + 256;
    const bool has1 = (j1 < NEXP);
    int a0, a1, a2, b0 = 0, b1 = 0, b2 = 0;
    decode_triple(j0, a0, a1, a2);
    if (has1) decode_triple(j1, b0, b1, b2);

    float s0 = 0.f, q0 = 0.f, s1 = 0.f, q1 = 0.f;
    for (int r = 0; r < SROWS; r += 4) {
        float4 va = *reinterpret_cast<const float4*>(&yc[a0][r]);
        float4 vb = *reinterpret_cast<const float4*>(&yc[a1][r]);
        float4 vc = *reinterpret_cast<const float4*>(&yc[a2][r]);
        float f;
        f = va.x * vb.x * vc.x; s0 += f; q0 += f * f;
        f = va.y * vb.y * vc.y; s0 += f; q0 += f * f;
        f = va.z * vb.z * vc.z; s0 += f; q0 += f * f;
        f = va.w * vb.w * vc.w; s0 += f; q0 += f * f;
        if (has1) {
            float4 wa = *reinterpret_cast<const float4*>(&yc[b0][r]);
            float4 wb = *reinterpret_cast<const float4*>(&yc[b1][r]);
            float4 wc = *reinterpret_cast<const float4*>(&yc[b2][r]);
            f = wa.x * wb.x * wc.x; s1 += f; q1 += f * f;
            f = wa.y * wb.y * wc.y; s1 += f; q1 += f * f;
            f = wa.z * wb.z * wc.z; s1 += f; q1 += f * f;
            f = wa.w * wb.w * wc.w; s1 += f; q1 += f * f;
        }
    }
    float* p = part + (size_t)blockIdx.x * PARTW;
    p[j0] = s0;
    p[NEXP + j0] = q0;
    if (has1) {
        p[j1] = s1;
        p[NEXP + j1] = q1;
    }
}

// ---------------- Pass 2: reduce partials, fold BN into scale/shift ---------
__global__ __launch_bounds__(256) void finalize_kernel(const float* __restrict__ part,
                                                       const float* __restrict__ w,
                                                       const float* __restrict__ b,
                                                       float* __restrict__ ss) {
    __shared__ float reds[8][FIN_FPB];
    __shared__ float redq[8][FIN_FPB];
    const int fl = threadIdx.x & 31;
    const int k  = threadIdx.x >> 5;              // slice 0..7
    const int f  = blockIdx.x * FIN_FPB + fl;
    float s = 0.f, q = 0.f;
    if (f < NEXP) {
        #pragma unroll 4
        for (int i = 0; i < SBLK / 8; ++i) {
            const float* p = part + (size_t)(k * (SBLK / 8) + i) * PARTW;
            s += p[f];
            q += p[NEXP + f];
        }
    }
    reds[k][fl] = s;
    redq[k][fl] = q;
    __syncthreads();
    if (threadIdx.x < FIN_FPB && f < NEXP) {
        float ts = 0.f, tq = 0.f;
        #pragma unroll
        for (int kk = 0; kk < 8; ++kk) { ts += reds[kk][fl]; tq += redq[kk][fl]; }
        const float inv_n = 1.0f / (float)NROWS;
        float mean = ts * inv_n;
        float var  = tq * inv_n - mean * mean;
        float scale = rsqrtf(var + BN_EPS) * w[f];
        ss[f] = scale;
        ss[NEXP + f] = b[f] - mean * scale;
    }
}

// ---------------- Pass 3: recompute feats, apply affine, store --------------
__global__ __launch_bounds__(256) void write_kernel(const float* __restrict__ x,
                                                    const float* __restrict__ ss,
                                                    float* __restrict__ out) {
    __shared__ float yc[NF][WPAD];
    const int tid = threadIdx.x;
    const int row0 = blockIdx.x * WROWS;

    for (int idx = tid; idx < WROWS * 12; idx += 256) {
        int r = idx / 12, c = idx - r * 12;
        yc[c + 1][r] = x[(size_t)row0 * 12 + idx];
    }
    for (int r = tid; r < WROWS; r += 256) yc[0][r] = 1.0f;

    const int j0 = tid;
    const int j1 = tid + 256;
    const bool has1 = (j1 < NEXP);
    int a0, a1, a2, b0 = 0, b1 = 0, b2 = 0;
    decode_triple(j0, a0, a1, a2);
    if (has1) decode_triple(j1, b0, b1, b2);
    const float sc0 = ss[j0], sh0 = ss[NEXP + j0];
    const float sc1 = has1 ? ss[j1] : 0.f, sh1 = has1 ? ss[NEXP + j1] : 0.f;
    __syncthreads();

    for (int r = 0; r < WROWS; r += 4) {
        float4 va = *reinterpret_cast<const float4*>(&yc[a0][r]);
        float4 vb = *reinterpret_cast<const float4*>(&yc[a1][r]);
        float4 vc = *reinterpret_cast<const float4*>(&yc[a2][r]);
        float* o = out + (size_t)(row0 + r) * NEXP + j0;
        o[0 * NEXP] = va.x * vb.x * vc.x * sc0 + sh0;
        o[1 * NEXP] = va.y * vb.y * vc.y * sc0 + sh0;
        o[2 * NEXP] = va.z * vb.z * vc.z * sc0 + sh0;
        o[3 * NEXP] = va.w * vb.w * vc.w * sc0 + sh0;
        if (has1) {
            float4 wa = *reinterpret_cast<const float4*>(&yc[b0][r]);
            float4 wb = *reinterpret_cast<const float4*>(&yc[b1][r]);
            float4 wc = *reinterpret_cast<const float4*>(&yc[b2][r]);
            float* o1 = out + (size_t)(row0 + r) * NEXP + j1;
            o1[0 * NEXP] = wa.x * wb.x * wc.x * sc1 + sh1;
            o1[1 * NEXP] = wa.y * wb.y * wc.y * sc1 + sh1;
            o1[2 * NEXP] = wa.z * wb.z * wc.z * sc1 + sh1;
            o1[3 * NEXP] = wa.w * wb.w * wc.w * sc1 + sh1;
        }
    }
}

extern "C" void kernel_launch(void* const* d_in, const int* in_sizes, int n_in,
                              void* d_out, int out_size, void* d_ws, size_t ws_size,
                              hipStream_t stream) {
    const float* x  = (const float*)d_in[0];
    const float* bw = (const float*)d_in[1];
    const float* bb = (const float*)d_in[2];
    float* out  = (float*)d_out;
    float* part = (float*)d_ws;                    // SBLK*908 floats = 1.86 MB
    float* ss   = part + (size_t)SBLK * PARTW;     // 908 floats scale/shift

    stats_kernel<<<SBLK, 256, 0, stream>>>(x, part);
    finalize_kernel<<<(NEXP + FIN_FPB - 1) / FIN_FPB, 256, 0, stream>>>(part, bw, bb, ss);
    write_kernel<<<NROWS / WROWS, 256, 0, stream>>>(x, ss, out);
}

// Round 9
// 44.157 us; speedup vs baseline: 3.4762x; 1.0068x over previous
//
#include <hip/hip_runtime.h>

#define NF 13          // y = [1, x1..x12]
#define NEXP 454       // unique monomials
#define NROWS 65536
#define BN_EPS 1e-5f
#define SBLK 512               // stats blocks
#define SROWS (NROWS / SBLK)   // 128 rows per stats block
#define PARTW 908              // per-block partial row: [454 sums | 454 sumsqs]
#define SPAD (SROWS + 4)       // padded column stride: 132 words, 16B-aligned
#define WROWS 32               // rows per write block (2048 blocks, 8/CU)
#define WPAD (WROWS + 4)       // 36 words
#define FIN_FPB 32             // features per finalize block

// Decode feature index j (0..453) -> nondecreasing triple (i0<=i1<=i2),
// lexicographic order over (i0,i1,i2), skipping (0,0,0).
__device__ __forceinline__ void decode_triple(int j, int& i0, int& i1, int& i2) {
    int g = j + 1;
    i0 = 0;
    for (;;) {
        int m = NF - i0;
        int c = m * (m + 1) / 2;
        if (g < c) break;
        g -= c; ++i0;
    }
    i1 = i0;
    for (;;) {
        int m = NF - i1;
        if (g < m) break;
        g -= m; ++i1;
    }
    i2 = i1 + g;
}

// ---------------- Pass 1: per-block partial sum / sumsq (no atomics) --------
// (R4/R8 version byte-for-byte: known good, ~8us LDS-issue-bound.)
__global__ __launch_bounds__(256) void stats_kernel(const float* __restrict__ x,
                                                    float* __restrict__ part) {
    __shared__ float yc[NF][SPAD];
    const int tid = threadIdx.x;
    const int row0 = blockIdx.x * SROWS;

    for (int idx = tid; idx < SROWS * 12; idx += 256) {
        int r = idx / 12, c = idx - r * 12;
        yc[c + 1][r] = x[(size_t)row0 * 12 + idx];
    }
    for (int r = tid; r < SROWS; r += 256) yc[0][r] = 1.0f;
    __syncthreads();

    const int j0 = tid;
    const int j1 = tid + 256;
    const bool has1 = (j1 < NEXP);
    int a0, a1, a2, b0 = 0, b1 = 0, b2 = 0;
    decode_triple(j0, a0, a1, a2);
    if (has1) decode_triple(j1, b0, b1, b2);

    float s0 = 0.f, q0 = 0.f, s1 = 0.f, q1 = 0.f;
    for (int r = 0; r < SROWS; r += 4) {
        float4 va = *reinterpret_cast<const float4*>(&yc[a0][r]);
        float4 vb = *reinterpret_cast<const float4*>(&yc[a1][r]);
        float4 vc = *reinterpret_cast<const float4*>(&yc[a2][r]);
        float f;
        f = va.x * vb.x * vc.x; s0 += f; q0 += f * f;
        f = va.y * vb.y * vc.y; s0 += f; q0 += f * f;
        f = va.z * vb.z * vc.z; s0 += f; q0 += f * f;
        f = va.w * vb.w * vc.w; s0 += f; q0 += f * f;
        if (has1) {
            float4 wa = *reinterpret_cast<const float4*>(&yc[b0][r]);
            float4 wb = *reinterpret_cast<const float4*>(&yc[b1][r]);
            float4 wc = *reinterpret_cast<const float4*>(&yc[b2][r]);
            f = wa.x * wb.x * wc.x; s1 += f; q1 += f * f;
            f = wa.y * wb.y * wc.y; s1 += f; q1 += f * f;
            f = wa.z * wb.z * wc.z; s1 += f; q1 += f * f;
            f = wa.w * wb.w * wc.w; s1 += f; q1 += f * f;
        }
    }
    float* p = part + (size_t)blockIdx.x * PARTW;
    p[j0] = s0;
    p[NEXP + j0] = q0;
    if (has1) {
        p[j1] = s1;
        p[NEXP + j1] = q1;
    }
}

// ---------------- Pass 2: reduce partials, fold BN into scale/shift ---------
__global__ __launch_bounds__(256) void finalize_kernel(const float* __restrict__ part,
                                                       const float* __restrict__ w,
                                                       const float* __restrict__ b,
                                                       float* __restrict__ ss) {
    __shared__ float reds[8][FIN_FPB];
    __shared__ float redq[8][FIN_FPB];
    const int fl = threadIdx.x & 31;
    const int k  = threadIdx.x >> 5;              // slice 0..7
    const int f  = blockIdx.x * FIN_FPB + fl;
    float s = 0.f, q = 0.f;
    if (f < NEXP) {
        #pragma unroll 4
        for (int i = 0; i < SBLK / 8; ++i) {
            const float* p = part + (size_t)(k * (SBLK / 8) + i) * PARTW;
            s += p[f];
            q += p[NEXP + f];
        }
    }
    reds[k][fl] = s;
    redq[k][fl] = q;
    __syncthreads();
    if (threadIdx.x < FIN_FPB && f < NEXP) {
        float ts = 0.f, tq = 0.f;
        #pragma unroll
        for (int kk = 0; kk < 8; ++kk) { ts += reds[kk][fl]; tq += redq[kk][fl]; }
        const float inv_n = 1.0f / (float)NROWS;
        float mean = ts * inv_n;
        float var  = tq * inv_n - mean * mean;
        float scale = rsqrtf(var + BN_EPS) * w[f];
        ss[f] = scale;
        ss[NEXP + f] = b[f] - mean * scale;
    }
}

// ---------------- Pass 3: recompute feats, apply affine, store --------------
// Thread t<227 owns FLAT features (2t, 2t+1): always-even index -> aligned
// float2 (dwordx2) stores, 512B contiguous per wave-instruction, half the
// store instructions of the scalar-dword version.
__global__ __launch_bounds__(256) void write_kernel(const float* __restrict__ x,
                                                    const float* __restrict__ ss,
                                                    float* __restrict__ out) {
    __shared__ float yc[NF][WPAD];
    const int tid = threadIdx.x;
    const int row0 = blockIdx.x * WROWS;

    for (int idx = tid; idx < WROWS * 12; idx += 256) {
        int r = idx / 12, c = idx - r * 12;
        yc[c + 1][r] = x[(size_t)row0 * 12 + idx];
    }
    for (int r = tid; r < WROWS; r += 256) yc[0][r] = 1.0f;

    const bool act = tid < NEXP / 2;     // 227 active threads
    const int j0 = 2 * tid;
    int a0 = 0, a1 = 0, a2 = 0, b0 = 0, b1 = 0, b2 = 0;
    float2 sc = {0.f, 0.f}, sh = {0.f, 0.f};
    if (act) {
        decode_triple(j0, a0, a1, a2);
        decode_triple(j0 + 1, b0, b1, b2);
        sc = *reinterpret_cast<const float2*>(&ss[j0]);          // even idx
        sh = *reinterpret_cast<const float2*>(&ss[NEXP + j0]);   // even idx
    }
    __syncthreads();

    if (act) {
        for (int r = 0; r < WROWS; r += 4) {
            float4 va = *reinterpret_cast<const float4*>(&yc[a0][r]);
            float4 vb = *reinterpret_cast<const float4*>(&yc[a1][r]);
            float4 vc = *reinterpret_cast<const float4*>(&yc[a2][r]);
            float4 wa = *reinterpret_cast<const float4*>(&yc[b0][r]);
            float4 wb = *reinterpret_cast<const float4*>(&yc[b1][r]);
            float4 wc = *reinterpret_cast<const float4*>(&yc[b2][r]);
            // (row*454 + j0) is even -> float2-aligned; row stride = 227 float2
            float2* o = reinterpret_cast<float2*>(
                out + (size_t)(row0 + r) * NEXP + j0);
            o[0 * (NEXP / 2)] = {va.x * vb.x * vc.x * sc.x + sh.x,
                                 wa.x * wb.x * wc.x * sc.y + sh.y};
            o[1 * (NEXP / 2)] = {va.y * vb.y * vc.y * sc.x + sh.x,
                                 wa.y * wb.y * wc.y * sc.y + sh.y};
            o[2 * (NEXP / 2)] = {va.z * vb.z * vc.z * sc.x + sh.x,
                                 wa.z * wb.z * wc.z * sc.y + sh.y};
            o[3 * (NEXP / 2)] = {va.w * vb.w * vc.w * sc.x + sh.x,
                                 wa.w * wb.w * wc.w * sc.y + sh.y};
        }
    }
}

extern "C" void kernel_launch(void* const* d_in, const int* in_sizes, int n_in,
                              void* d_out, int out_size, void* d_ws, size_t ws_size,
                              hipStream_t stream) {
    const float* x  = (const float*)d_in[0];
    const float* bw = (const float*)d_in[1];
    const float* bb = (const float*)d_in[2];
    float* out  = (float*)d_out;
    float* part = (float*)d_ws;                    // SBLK*908 floats = 1.86 MB
    float* ss   = part + (size_t)SBLK * PARTW;     // 908 floats scale/shift

    stats_kernel<<<SBLK, 256, 0, stream>>>(x, part);
    finalize_kernel<<<(NEXP + FIN_FPB - 1) / FIN_FPB, 256, 0, stream>>>(part, bw, bb, ss);
    write_kernel<<<NROWS / WROWS, 256, 0, stream>>>(x, ss, out);
}